// Round 6
// baseline (284.540 us; speedup 1.0000x reference)
//
#include <hip/hip_runtime.h>
#include <math.h>

#define D 128
#define EPS_NORM 1e-12f
#define SPLIT 4

__device__ __forceinline__ unsigned int f32_to_bf16(float f) {
    unsigned int u = __float_as_uint(f);
    return (u + 0x7FFFu + ((u >> 16) & 1u)) >> 16;
}
__device__ __forceinline__ float bf_lo(unsigned int w) { return __uint_as_float(w << 16); }
__device__ __forceinline__ float bf_hi(unsigned int w) { return __uint_as_float(w & 0xFFFF0000u); }

__device__ __forceinline__ float dot8(uint4 sw, uint4 cw, uint4 dw) {
    float p;
    p = bf_lo(sw.x) * bf_lo(cw.x) * bf_lo(dw.x);
    p = fmaf(bf_hi(sw.x) * bf_hi(cw.x), bf_hi(dw.x), p);
    p = fmaf(bf_lo(sw.y) * bf_lo(cw.y), bf_lo(dw.y), p);
    p = fmaf(bf_hi(sw.y) * bf_hi(cw.y), bf_hi(dw.y), p);
    p = fmaf(bf_lo(sw.z) * bf_lo(cw.z), bf_lo(dw.z), p);
    p = fmaf(bf_hi(sw.z) * bf_hi(cw.z), bf_hi(dw.z), p);
    p = fmaf(bf_lo(sw.w) * bf_lo(cw.w), bf_lo(dw.w), p);
    p = fmaf(bf_hi(sw.w) * bf_hi(cw.w), bf_hi(dw.w), p);
    return p;
}

// Fused prep: [0,nbz) z-normalize+bf16-pack; [nbz,nbz+nbc) cos-pack; rest: type histogram.
__global__ void prep_kernel(const float* __restrict__ z, unsigned int* __restrict__ zn, int N,
                            const float* __restrict__ phase, unsigned int* __restrict__ ct, int n2,
                            const int* __restrict__ et, int E, int* __restrict__ hist, // = starts+1
                            int R, int nbz, int nbc, int nbh) {
    __shared__ int lh[1024];
    int bx = (int)blockIdx.x;
    if (bx < nbz) {
        int w    = bx * 4 + (threadIdx.x >> 6);
        int lane = threadIdx.x & 63;
        int half = lane >> 5;
        int hl   = lane & 31;
        int row  = w * 2 + half;
        if (row >= N) return;
        float4 v = reinterpret_cast<const float4*>(z + (size_t)row * D)[hl];
        float s = v.x * v.x + v.y * v.y + v.z * v.z + v.w * v.w;
#pragma unroll
        for (int off = 16; off > 0; off >>= 1) s += __shfl_xor(s, off, 32);
        float inv = 1.0f / fmaxf(sqrtf(s), EPS_NORM);
        uint2 o;
        o.x = (f32_to_bf16(v.y * inv) << 16) | f32_to_bf16(v.x * inv);
        o.y = (f32_to_bf16(v.w * inv) << 16) | f32_to_bf16(v.z * inv);
        reinterpret_cast<uint2*>(zn + (size_t)row * (D / 2))[hl] = o;
    } else if (bx < nbz + nbc) {
        int i = (bx - nbz) * blockDim.x + threadIdx.x;
        if (i < n2) {
            float a = cosf(phase[2 * i]);
            float b = cosf(phase[2 * i + 1]);
            ct[i] = (f32_to_bf16(b) << 16) | f32_to_bf16(a);
        }
    } else {
        for (int i = threadIdx.x; i < R; i += blockDim.x) lh[i] = 0;
        __syncthreads();
        int b = bx - nbz - nbc;
        for (int e = b * blockDim.x + threadIdx.x; e < E; e += nbh * blockDim.x)
            atomicAdd(&lh[__builtin_nontemporal_load(et + e)], 1);
        __syncthreads();
        for (int i = threadIdx.x; i < R; i += blockDim.x)
            if (lh[i]) atomicAdd(&hist[i], lh[i]);
    }
}

// Single-block scan: starts[0]=0, starts[i+1]=sum counts[0..i]; cursors[i]=starts[i]. R<=1024.
__global__ void scan_kernel(int* __restrict__ starts, int* __restrict__ cursors, int R) {
    __shared__ int buf[1024];
    int tid = threadIdx.x;
    int v = (tid < R) ? starts[tid + 1] : 0;
    buf[tid] = v;
    __syncthreads();
    for (int off = 1; off < 1024; off <<= 1) {
        int x = (tid >= off) ? buf[tid - off] : 0;
        __syncthreads();
        buf[tid] += x;
        __syncthreads();
    }
    if (tid < R) {
        starts[tid + 1] = buf[tid];
        cursors[tid] = (tid == 0) ? 0 : buf[tid - 1];
    }
    if (tid == 0) starts[0] = 0;
}

// Scatter edges into type-sorted record array: rec[pos] = {src, dst, orig_e}
__global__ void scatter_kernel(const int* __restrict__ ei, const int* __restrict__ et, int E,
                               int* __restrict__ cursors, int4* __restrict__ rec) {
    int idx = (int)(blockIdx.x * blockDim.x + threadIdx.x);
    int n   = (int)(gridDim.x * blockDim.x);
    for (int e = idx; e < E; e += n) {
        int s = __builtin_nontemporal_load(ei + e);
        int d = __builtin_nontemporal_load(ei + E + e);
        int t = __builtin_nontemporal_load(et + e);
        int pos = atomicAdd(&cursors[t], 1);
        rec[pos] = make_int4(s, d, e, 0);
    }
}

// One block per type-slice: ct row in registers (via LDS broadcast), 2 gathers/edge.
__global__ __launch_bounds__(256, 6) void edge_bucket_kernel(
    const unsigned int* __restrict__ zn, const unsigned int* __restrict__ ct,
    const int* __restrict__ starts, const int4* __restrict__ rec,
    float* __restrict__ out) {
    const uint4* zn4 = reinterpret_cast<const uint4*>(zn);
    const uint4* ct4 = reinterpret_cast<const uint4*>(ct);
    int t = (int)blockIdx.x / SPLIT, j = (int)blockIdx.x % SPLIT;
    int lo = starts[t], hi = starts[t + 1], len = hi - lo;
    int s0 = lo + (int)(((long long)len * j) / SPLIT);
    int s1 = lo + (int)(((long long)len * (j + 1)) / SPLIT);
    __shared__ uint4 ctl[16];
    if (threadIdx.x < 16) ctl[threadIdx.x] = ct4[(size_t)t * 16 + threadIdx.x];
    __syncthreads();
    int l = threadIdx.x & 15, g = threadIdx.x >> 4;
    uint4 C = ctl[l]; // this lane's 16 B of the type's cos row, in registers
    int nq = (s1 - s0) >> 2;
    for (int q = g; q < nq; q += 16) {
        int i = s0 + q * 4;
        int4 r0 = rec[i], r1 = rec[i + 1], r2 = rec[i + 2], r3 = rec[i + 3];
        uint4 A0 = zn4[(size_t)r0.x * 16 + l];
        uint4 B0 = zn4[(size_t)r0.y * 16 + l];
        uint4 A1 = zn4[(size_t)r1.x * 16 + l];
        uint4 B1 = zn4[(size_t)r1.y * 16 + l];
        uint4 A2 = zn4[(size_t)r2.x * 16 + l];
        uint4 B2 = zn4[(size_t)r2.y * 16 + l];
        uint4 A3 = zn4[(size_t)r3.x * 16 + l];
        uint4 B3 = zn4[(size_t)r3.y * 16 + l];
        asm volatile("" ::: "memory");
        float p0 = dot8(A0, C, B0);
        float p1 = dot8(A1, C, B1);
        float p2 = dot8(A2, C, B2);
        float p3 = dot8(A3, C, B3);
#pragma unroll
        for (int off = 8; off > 0; off >>= 1) {
            p0 += __shfl_xor(p0, off, 64);
            p1 += __shfl_xor(p1, off, 64);
            p2 += __shfl_xor(p2, off, 64);
            p3 += __shfl_xor(p3, off, 64);
        }
        if (l < 4) {
            int   oe = (l == 0) ? r0.z : (l == 1) ? r1.z : (l == 2) ? r2.z : r3.z;
            float v  = (l == 0) ? p0   : (l == 1) ? p1   : (l == 2) ? p2   : p3;
            __builtin_nontemporal_store(v, out + oe);
        }
    }
    for (int i = s0 + nq * 4 + g; i < s1; i += 16) {
        int4 r = rec[i];
        uint4 A = zn4[(size_t)r.x * 16 + l];
        uint4 B = zn4[(size_t)r.y * 16 + l];
        float p = dot8(A, C, B);
#pragma unroll
        for (int off = 8; off > 0; off >>= 1) p += __shfl_xor(p, off, 64);
        if (l == 0) __builtin_nontemporal_store(p, out + r.z);
    }
}

// ---------------- fallback (ws too small / R too big): R5 path ----------------
#define ISSUE(S, ev)                                                      \
    int4 S##s = *reinterpret_cast<const int4*>(ei + (ev));                \
    int4 S##d = *reinterpret_cast<const int4*>(ei + E + (ev));            \
    int4 S##t = *reinterpret_cast<const int4*>(et + (ev));                \
    uint4 S##A0 = zn4[(size_t)S##s.x * 16 + l];                           \
    uint4 S##B0 = zn4[(size_t)S##d.x * 16 + l];                           \
    uint4 S##C0 = ct4[(size_t)S##t.x * 16 + l];                           \
    uint4 S##A1 = zn4[(size_t)S##s.y * 16 + l];                           \
    uint4 S##B1 = zn4[(size_t)S##d.y * 16 + l];                           \
    uint4 S##C1 = ct4[(size_t)S##t.y * 16 + l];                           \
    uint4 S##A2 = zn4[(size_t)S##s.z * 16 + l];                           \
    uint4 S##B2 = zn4[(size_t)S##d.z * 16 + l];                           \
    uint4 S##C2 = ct4[(size_t)S##t.z * 16 + l];                           \
    uint4 S##A3 = zn4[(size_t)S##s.w * 16 + l];                           \
    uint4 S##B3 = zn4[(size_t)S##d.w * 16 + l];                           \
    uint4 S##C3 = ct4[(size_t)S##t.w * 16 + l];

#define COMPUTE(S, ebase)                                                 \
    {                                                                     \
        float p0 = dot8(S##A0, S##C0, S##B0);                             \
        float p1 = dot8(S##A1, S##C1, S##B1);                             \
        float p2 = dot8(S##A2, S##C2, S##B2);                             \
        float p3 = dot8(S##A3, S##C3, S##B3);                             \
        _Pragma("unroll")                                                 \
        for (int off = 8; off > 0; off >>= 1) {                           \
            p0 += __shfl_xor(p0, off, 64);                                \
            p1 += __shfl_xor(p1, off, 64);                                \
            p2 += __shfl_xor(p2, off, 64);                                \
            p3 += __shfl_xor(p3, off, 64);                                \
        }                                                                 \
        float v = (l == 0) ? p0 : (l == 1) ? p1 : (l == 2) ? p2 : p3;     \
        if (l < 4) out[(ebase) + l] = v;                                  \
    }

__global__ __launch_bounds__(256, 4) void edge_kernel_v5(
    const unsigned int* __restrict__ zn, const unsigned int* __restrict__ ct,
    const int* __restrict__ ei, const int* __restrict__ et,
    float* __restrict__ out, int E) {
    const uint4* zn4 = reinterpret_cast<const uint4*>(zn);
    const uint4* ct4 = reinterpret_cast<const uint4*>(ct);
    int tid = (int)(blockIdx.x * blockDim.x + threadIdx.x);
    int gid = tid >> 4;
    int l = threadIdx.x & 15;
    int ngroups = (int)((gridDim.x * blockDim.x) >> 4);
    int stride = ngroups * 8;
    int E8 = E & ~7;
    for (int e = gid * 8; e + 8 <= E8; e += stride) {
        ISSUE(P, e)
        ISSUE(Q, e + 4)
        asm volatile("" ::: "memory");
        COMPUTE(P, e)
        COMPUTE(Q, e + 4)
    }
    for (int e2 = E8 + gid; e2 < E; e2 += ngroups) {
        int s = ei[e2], dd = ei[E + e2], t = et[e2];
        uint4 A = zn4[(size_t)s * 16 + l];
        uint4 B = zn4[(size_t)dd * 16 + l];
        uint4 Cc = ct4[(size_t)t * 16 + l];
        float p = dot8(A, Cc, B);
#pragma unroll
        for (int off = 8; off > 0; off >>= 1) p += __shfl_xor(p, off, 64);
        if (l == 0) out[e2] = p;
    }
}

extern "C" void kernel_launch(void* const* d_in, const int* in_sizes, int n_in,
                              void* d_out, int out_size, void* d_ws, size_t ws_size,
                              hipStream_t stream) {
    const float* z          = (const float*)d_in[0];
    const int*   edge_index = (const int*)d_in[1];   // [2, E] int32
    const int*   edge_type  = (const int*)d_in[2];   // [E] int32
    const float* phase_rel  = (const float*)d_in[3]; // [R, D]
    float* out = (float*)d_out;

    const int N      = in_sizes[0] / D;
    const int E      = in_sizes[2];
    const int nphase = in_sizes[3];      // R * D
    const int R      = nphase / D;
    const int n2     = nphase / 2;

    // ws layout (16 B aligned chunks)
    const size_t zn_bytes  = (size_t)N * (D / 2) * sizeof(unsigned int); // 25.6 MB
    const size_t ct_bytes  = ((size_t)n2 * sizeof(unsigned int) + 15) & ~(size_t)15;
    const size_t cnt_bytes = ((size_t)(2 * R + 1) * sizeof(int) + 15) & ~(size_t)15;
    const size_t rec_bytes = (size_t)E * sizeof(int4);                   // 10.24 MB

    unsigned int* zn      = (unsigned int*)d_ws;
    unsigned int* ct      = (unsigned int*)((char*)d_ws + zn_bytes);
    int*          starts  = (int*)((char*)d_ws + zn_bytes + ct_bytes);   // [R+1]
    int*          cursors = starts + (R + 1);                            // [R]
    int4*         rec     = (int4*)((char*)d_ws + zn_bytes + ct_bytes + cnt_bytes);

    const int nbz = (N + 7) / 8;
    const int nbc = (n2 + 255) / 256;

    if (ws_size >= zn_bytes + ct_bytes + cnt_bytes + rec_bytes && R <= 1024) {
        const int nbh = 256;
        // zero histogram + cursors (memset node is graph-capture legal)
        hipMemsetAsync(starts, 0, (size_t)(2 * R + 1) * sizeof(int), stream);
        // prep: norm+pack z | cos-pack | type histogram
        prep_kernel<<<nbz + nbc + nbh, 256, 0, stream>>>(
            z, zn, N, phase_rel, ct, n2, edge_type, E, starts + 1, R, nbz, nbc, nbh);
        scan_kernel<<<1, 1024, 0, stream>>>(starts, cursors, R);
        scatter_kernel<<<512, 256, 0, stream>>>(edge_index, edge_type, E, cursors, rec);
        edge_bucket_kernel<<<R * SPLIT, 256, 0, stream>>>(zn, ct, starts, rec, out);
    } else if (ws_size >= zn_bytes + ct_bytes) {
        prep_kernel<<<nbz + nbc, 256, 0, stream>>>(
            z, zn, N, phase_rel, ct, n2, edge_type, E, (int*)nullptr, 0, nbz, nbc, 0);
        edge_kernel_v5<<<2048, 256, 0, stream>>>(zn, ct, edge_index, edge_type, out, E);
    }
}

// Round 7
// 63.541 us; speedup vs baseline: 4.4780x; 4.4780x over previous
//
#include <hip/hip_runtime.h>
#include <math.h>

#define D 128
#define EPS_NORM 1e-12f

__device__ __forceinline__ unsigned int f32_to_bf16(float f) {
    unsigned int u = __float_as_uint(f);
    return (u + 0x7FFFu + ((u >> 16) & 1u)) >> 16;
}
__device__ __forceinline__ float bf_lo(unsigned int w) { return __uint_as_float(w << 16); }
__device__ __forceinline__ float bf_hi(unsigned int w) { return __uint_as_float(w & 0xFFFF0000u); }

// Fused precompute: blocks [0, nbz) L2-normalize + bf16-pack z (2 rows/wave);
// blocks [nbz, ...) cos-pack the phase table. Streaming reads are non-temporal
// so they don't evict the zn table being built in L2.
__global__ void prep_kernel(const float* __restrict__ z, unsigned int* __restrict__ zn, int N,
                            const float* __restrict__ phase, unsigned int* __restrict__ ct, int n2,
                            int nbz) {
    if ((int)blockIdx.x < nbz) {
        int w    = blockIdx.x * 4 + (threadIdx.x >> 6);
        int lane = threadIdx.x & 63;
        int half = lane >> 5;
        int hl   = lane & 31;
        int row  = w * 2 + half;
        if (row >= N) return;
        const float4* src = reinterpret_cast<const float4*>(z + (size_t)row * D) + hl;
        float4 v;
        v.x = __builtin_nontemporal_load(&src->x);
        v.y = __builtin_nontemporal_load(&src->y);
        v.z = __builtin_nontemporal_load(&src->z);
        v.w = __builtin_nontemporal_load(&src->w);
        float s = v.x * v.x + v.y * v.y + v.z * v.z + v.w * v.w;
#pragma unroll
        for (int off = 16; off > 0; off >>= 1) s += __shfl_xor(s, off, 32);
        float inv = 1.0f / fmaxf(sqrtf(s), EPS_NORM);
        uint2 o;
        o.x = (f32_to_bf16(v.y * inv) << 16) | f32_to_bf16(v.x * inv);
        o.y = (f32_to_bf16(v.w * inv) << 16) | f32_to_bf16(v.z * inv);
        reinterpret_cast<uint2*>(zn + (size_t)row * (D / 2))[hl] = o;
    } else {
        int i = (blockIdx.x - nbz) * blockDim.x + threadIdx.x;
        if (i < n2) {
            float a = cosf(__builtin_nontemporal_load(phase + 2 * i));
            float b = cosf(__builtin_nontemporal_load(phase + 2 * i + 1));
            ct[i] = (f32_to_bf16(b) << 16) | f32_to_bf16(a);
        }
    }
}

__device__ __forceinline__ float dot8(uint4 sw, uint4 cw, uint4 dw) {
    float p;
    p = bf_lo(sw.x) * bf_lo(cw.x) * bf_lo(dw.x);
    p = fmaf(bf_hi(sw.x) * bf_hi(cw.x), bf_hi(dw.x), p);
    p = fmaf(bf_lo(sw.y) * bf_lo(cw.y), bf_lo(dw.y), p);
    p = fmaf(bf_hi(sw.y) * bf_hi(cw.y), bf_hi(dw.y), p);
    p = fmaf(bf_lo(sw.z) * bf_lo(cw.z), bf_lo(dw.z), p);
    p = fmaf(bf_hi(sw.z) * bf_hi(cw.z), bf_hi(dw.z), p);
    p = fmaf(bf_lo(sw.w) * bf_lo(cw.w), bf_lo(dw.w), p);
    p = fmaf(bf_hi(sw.w) * bf_hi(cw.w), bf_hi(dw.w), p);
    return p;
}

// Issue all loads for 4 edges of stage S (3 int4 index loads + 12 uint4 gathers)
#define ISSUE(S, ev)                                                      \
    int4 S##s = *reinterpret_cast<const int4*>(ei + (ev));                \
    int4 S##d = *reinterpret_cast<const int4*>(ei + E + (ev));            \
    int4 S##t = *reinterpret_cast<const int4*>(et + (ev));                \
    uint4 S##A0 = zn4[(size_t)S##s.x * 16 + l];                           \
    uint4 S##B0 = zn4[(size_t)S##d.x * 16 + l];                           \
    uint4 S##C0 = ct4[(size_t)S##t.x * 16 + l];                           \
    uint4 S##A1 = zn4[(size_t)S##s.y * 16 + l];                           \
    uint4 S##B1 = zn4[(size_t)S##d.y * 16 + l];                           \
    uint4 S##C1 = ct4[(size_t)S##t.y * 16 + l];                           \
    uint4 S##A2 = zn4[(size_t)S##s.z * 16 + l];                           \
    uint4 S##B2 = zn4[(size_t)S##d.z * 16 + l];                           \
    uint4 S##C2 = ct4[(size_t)S##t.z * 16 + l];                           \
    uint4 S##A3 = zn4[(size_t)S##s.w * 16 + l];                           \
    uint4 S##B3 = zn4[(size_t)S##d.w * 16 + l];                           \
    uint4 S##C3 = ct4[(size_t)S##t.w * 16 + l];

#define COMPUTE(S, ebase)                                                 \
    {                                                                     \
        float p0 = dot8(S##A0, S##C0, S##B0);                             \
        float p1 = dot8(S##A1, S##C1, S##B1);                             \
        float p2 = dot8(S##A2, S##C2, S##B2);                             \
        float p3 = dot8(S##A3, S##C3, S##B3);                             \
        _Pragma("unroll")                                                 \
        for (int off = 8; off > 0; off >>= 1) {                           \
            p0 += __shfl_xor(p0, off, 64);                                \
            p1 += __shfl_xor(p1, off, 64);                                \
            p2 += __shfl_xor(p2, off, 64);                                \
            p3 += __shfl_xor(p3, off, 64);                                \
        }                                                                 \
        float v = (l == 0) ? p0 : (l == 1) ? p1 : (l == 2) ? p2 : p3;     \
        if (l < 4) out[(ebase) + l] = v;                                  \
    }

// 16 lanes/edge, 8 edges per group-iteration, ALL 30 loads issued before
// any compute (asm memory fence prevents load sinking).
__global__ __launch_bounds__(256, 4) void edge_kernel_v5(
    const unsigned int* __restrict__ zn,   // [N, D/2]
    const unsigned int* __restrict__ ct,   // [R, D/2]
    const int* __restrict__ ei,            // [2, E]
    const int* __restrict__ et,            // [E]
    float* __restrict__ out, int E) {
    const uint4* zn4 = reinterpret_cast<const uint4*>(zn); // row = node*16 + l
    const uint4* ct4 = reinterpret_cast<const uint4*>(ct);
    int tid     = (int)(blockIdx.x * blockDim.x + threadIdx.x);
    int gid     = tid >> 4;
    int l       = threadIdx.x & 15;
    int ngroups = (int)((gridDim.x * blockDim.x) >> 4);
    int stride  = ngroups * 8;
    int E8      = E & ~7;

    for (int e = gid * 8; e + 8 <= E8; e += stride) {
        ISSUE(P, e)
        ISSUE(Q, e + 4)
        asm volatile("" ::: "memory"); // loads above cannot sink below
        COMPUTE(P, e)
        COMPUTE(Q, e + 4)
    }
    // tail (E % 8 edges)
    for (int e2 = E8 + gid; e2 < E; e2 += ngroups) {
        int s = ei[e2], dd = ei[E + e2], t = et[e2];
        uint4 A = zn4[(size_t)s * 16 + l];
        uint4 B = zn4[(size_t)dd * 16 + l];
        uint4 C = ct4[(size_t)t * 16 + l];
        float p = dot8(A, C, B);
#pragma unroll
        for (int off = 8; off > 0; off >>= 1) p += __shfl_xor(p, off, 64);
        if (l == 0) out[e2] = p;
    }
}

extern "C" void kernel_launch(void* const* d_in, const int* in_sizes, int n_in,
                              void* d_out, int out_size, void* d_ws, size_t ws_size,
                              hipStream_t stream) {
    const float* z          = (const float*)d_in[0];
    const int*   edge_index = (const int*)d_in[1];   // [2, E] int32
    const int*   edge_type  = (const int*)d_in[2];   // [E] int32
    const float* phase_rel  = (const float*)d_in[3]; // [R, D]
    float* out = (float*)d_out;

    const int N      = in_sizes[0] / D;
    const int E      = in_sizes[2];
    const int nphase = in_sizes[3]; // R * D

    const size_t zn_bytes = (size_t)N * (D / 2) * sizeof(unsigned int); // 25.6 MB

    unsigned int* zn = (unsigned int*)d_ws;
    unsigned int* ct = (unsigned int*)((char*)d_ws + zn_bytes);
    (void)ws_size;

    // 1) fused precompute: norm+pack z, cos+pack phase
    const int n2  = nphase / 2;
    const int nbz = (N + 7) / 8;
    const int nbc = (n2 + 255) / 256;
    prep_kernel<<<nbz + nbc, 256, 0, stream>>>(z, zn, N, phase_rel, ct, n2, nbz);

    // 2) edge dots: 2048 blocks, 16-lane groups, 8 edges (30 loads) in flight each
    edge_kernel_v5<<<2048, 256, 0, stream>>>(zn, ct, edge_index, edge_type, out, E);
}

// Round 8
// 60.785 us; speedup vs baseline: 4.6811x; 1.0453x over previous
//
#include <hip/hip_runtime.h>
#include <math.h>

#define D 128
#define EPS_NORM 1e-12f

typedef __attribute__((address_space(3))) unsigned int lds_u32;
typedef __attribute__((address_space(1))) const unsigned int glb_u32;

__device__ __forceinline__ unsigned int f32_to_bf16(float f) {
    unsigned int u = __float_as_uint(f);
    return (u + 0x7FFFu + ((u >> 16) & 1u)) >> 16;
}
__device__ __forceinline__ float bf_lo(unsigned int w) { return __uint_as_float(w << 16); }
__device__ __forceinline__ float bf_hi(unsigned int w) { return __uint_as_float(w & 0xFFFF0000u); }

// Fused precompute: [0,nbz) L2-normalize + bf16-pack z (2 rows/wave, float4 loads);
// [nbz,...) cos-pack phase table.
__global__ void prep_kernel(const float* __restrict__ z, unsigned int* __restrict__ zn, int N,
                            const float* __restrict__ phase, unsigned int* __restrict__ ct, int n2,
                            int nbz) {
    if ((int)blockIdx.x < nbz) {
        int w    = blockIdx.x * 4 + (threadIdx.x >> 6);
        int lane = threadIdx.x & 63;
        int half = lane >> 5;
        int hl   = lane & 31;
        int row  = w * 2 + half;
        if (row >= N) return;
        float4 v = reinterpret_cast<const float4*>(z + (size_t)row * D)[hl];
        float s = v.x * v.x + v.y * v.y + v.z * v.z + v.w * v.w;
#pragma unroll
        for (int off = 16; off > 0; off >>= 1) s += __shfl_xor(s, off, 32);
        float inv = 1.0f / fmaxf(sqrtf(s), EPS_NORM);
        uint2 o;
        o.x = (f32_to_bf16(v.y * inv) << 16) | f32_to_bf16(v.x * inv);
        o.y = (f32_to_bf16(v.w * inv) << 16) | f32_to_bf16(v.z * inv);
        reinterpret_cast<uint2*>(zn + (size_t)row * (D / 2))[hl] = o;
    } else {
        int i = (blockIdx.x - nbz) * blockDim.x + threadIdx.x;
        if (i < n2) {
            float a = cosf(phase[2 * i]);
            float b = cosf(phase[2 * i + 1]);
            ct[i] = (f32_to_bf16(b) << 16) | f32_to_bf16(a);
        }
    }
}

__device__ __forceinline__ float dot8(uint4 sw, uint4 cw, uint4 dw) {
    float p;
    p = bf_lo(sw.x) * bf_lo(cw.x) * bf_lo(dw.x);
    p = fmaf(bf_hi(sw.x) * bf_hi(cw.x), bf_hi(dw.x), p);
    p = fmaf(bf_lo(sw.y) * bf_lo(cw.y), bf_lo(dw.y), p);
    p = fmaf(bf_hi(sw.y) * bf_hi(cw.y), bf_hi(dw.y), p);
    p = fmaf(bf_lo(sw.z) * bf_lo(cw.z), bf_lo(dw.z), p);
    p = fmaf(bf_hi(sw.z) * bf_hi(cw.z), bf_hi(dw.z), p);
    p = fmaf(bf_lo(sw.w) * bf_lo(cw.w), bf_lo(dw.w), p);
    p = fmaf(bf_hi(sw.w) * bf_hi(cw.w), bf_hi(dw.w), p);
    return p;
}

// 8 edges per wave per iteration. 16 zn rows (4 KB) staged via 4 global_load_lds
// dwordx4 (payload bypasses VGPRs -> high MLP at full occupancy). LDS slab is
// wave-private: no barriers, one vmcnt(0) per iteration.
__global__ __launch_bounds__(256, 8) void edge_kernel_v6(
    const unsigned int* __restrict__ zn,   // [N, D/2] bf16x2
    const unsigned int* __restrict__ ct,   // [R, D/2] bf16x2
    const int* __restrict__ ei,            // [2, E]
    const int* __restrict__ et,            // [E]
    float* __restrict__ out, int E) {
    __shared__ __align__(16) unsigned int smem[4 * 1024]; // 4 waves * 4 KB
    const uint4* ct4 = reinterpret_cast<const uint4*>(ct);
    const uint4* zn4 = reinterpret_cast<const uint4*>(zn);

    int wave = (int)(threadIdx.x >> 6);
    int lane = (int)(threadIdx.x & 63);
    int l16  = lane & 15;
    int g    = lane >> 4;                 // 16-lane group 0..3
    unsigned int* wb = smem + wave * 1024;

    int gwid   = (int)((blockIdx.x * blockDim.x + threadIdx.x) >> 6);
    int nwaves = (int)((gridDim.x * blockDim.x) >> 6);
    int E8     = E & ~7;

    for (int e = gwid * 8; e + 8 <= E8; e += nwaves * 8) {
        // lanes 0-7: src ids; 8-15: dst ids; 16-23: types
        int idx = 0;
        if (lane < 8)       idx = ei[e + lane];
        else if (lane < 16) idx = ei[E + e + (lane - 8)];
        else if (lane < 24) idx = et[e + (lane - 16)];

        int r  = lane >> 4;                // subrow 0..3 this lane stages
        int sA = __shfl(idx, r);           // src of edges 0-3
        int sB = __shfl(idx, 4 + r);       // src of edges 4-7
        int dA = __shfl(idx, 8 + r);       // dst of edges 0-3
        int dB = __shfl(idx, 12 + r);      // dst of edges 4-7

        const char* znb = (const char*)zn;
        size_t off = (size_t)(l16 * 16);
        // src edge j -> wb uints [j*64, j*64+64); dst edge j -> wb + 512 + j*64
        __builtin_amdgcn_global_load_lds((glb_u32*)(znb + (size_t)sA * 256 + off), (lds_u32*)(wb + 0),   16, 0, 0);
        __builtin_amdgcn_global_load_lds((glb_u32*)(znb + (size_t)sB * 256 + off), (lds_u32*)(wb + 256), 16, 0, 0);
        __builtin_amdgcn_global_load_lds((glb_u32*)(znb + (size_t)dA * 256 + off), (lds_u32*)(wb + 512), 16, 0, 0);
        __builtin_amdgcn_global_load_lds((glb_u32*)(znb + (size_t)dB * 256 + off), (lds_u32*)(wb + 768), 16, 0, 0);

        // ct rows for this group's two edges (L2-resident, via VGPR)
        int t0 = __shfl(idx, 16 + 2 * g);
        int t1 = __shfl(idx, 16 + 2 * g + 1);
        uint4 C0 = ct4[(size_t)t0 * 16 + l16];
        uint4 C1 = ct4[(size_t)t1 * 16 + l16];

        asm volatile("s_waitcnt vmcnt(0)" ::: "memory");

        int j0 = 2 * g, j1 = 2 * g + 1;
        uint4 A0 = *reinterpret_cast<const uint4*>(wb + j0 * 64 + l16 * 4);
        uint4 B0 = *reinterpret_cast<const uint4*>(wb + 512 + j0 * 64 + l16 * 4);
        float p0 = dot8(A0, C0, B0);
        uint4 A1 = *reinterpret_cast<const uint4*>(wb + j1 * 64 + l16 * 4);
        uint4 B1 = *reinterpret_cast<const uint4*>(wb + 512 + j1 * 64 + l16 * 4);
        float p1 = dot8(A1, C1, B1);
#pragma unroll
        for (int o = 8; o > 0; o >>= 1) {
            p0 += __shfl_xor(p0, o, 64);
            p1 += __shfl_xor(p1, o, 64);
        }
        if (l16 == 0) {
            out[e + j0] = p0;
            out[e + j1] = p1;
        }
    }
    // generic tail (E % 8 edges; not hit for E=640000)
    int ngroups = nwaves * 4;
    int gidx    = gwid * 4 + g;
    for (int e2 = E8 + gidx; e2 < E; e2 += ngroups) {
        int s = ei[e2], dd = ei[E + e2], t = et[e2];
        uint4 A = zn4[(size_t)s * 16 + l16];
        uint4 B = zn4[(size_t)dd * 16 + l16];
        uint4 C = ct4[(size_t)t * 16 + l16];
        float p = dot8(A, C, B);
#pragma unroll
        for (int o = 8; o > 0; o >>= 1) p += __shfl_xor(p, o, 64);
        if (l16 == 0) out[e2] = p;
    }
}

extern "C" void kernel_launch(void* const* d_in, const int* in_sizes, int n_in,
                              void* d_out, int out_size, void* d_ws, size_t ws_size,
                              hipStream_t stream) {
    const float* z          = (const float*)d_in[0];
    const int*   edge_index = (const int*)d_in[1];   // [2, E] int32
    const int*   edge_type  = (const int*)d_in[2];   // [E] int32
    const float* phase_rel  = (const float*)d_in[3]; // [R, D]
    float* out = (float*)d_out;

    const int N      = in_sizes[0] / D;
    const int E      = in_sizes[2];
    const int nphase = in_sizes[3]; // R * D

    const size_t zn_bytes = (size_t)N * (D / 2) * sizeof(unsigned int); // 25.6 MB

    unsigned int* zn = (unsigned int*)d_ws;
    unsigned int* ct = (unsigned int*)((char*)d_ws + zn_bytes);
    (void)ws_size;

    // 1) fused precompute: norm+pack z, cos+pack phase
    const int n2  = nphase / 2;
    const int nbz = (N + 7) / 8;
    const int nbc = (n2 + 255) / 256;
    prep_kernel<<<nbz + nbc, 256, 0, stream>>>(z, zn, N, phase_rel, ct, n2, nbz);

    // 2) edge dots: DMA-staged gathers, 2048 blocks * 4 waves * 8 edges/iter
    edge_kernel_v6<<<2048, 256, 0, stream>>>(zn, ct, edge_index, edge_type, out, E);
}